// Round 1
// baseline (310.973 us; speedup 1.0000x reference)
//
#include <hip/hip_runtime.h>
#include <cstdint>
#include <cstddef>

typedef unsigned short ushort_t;
typedef __attribute__((ext_vector_type(8))) short bf16x8;
typedef __attribute__((ext_vector_type(4))) float f32x4;

#define MROWS 16384
#define KDIM  1024
#define NDIM  2048
#define HDIM  512

static __device__ __forceinline__ unsigned short f2bf(float f) {
    unsigned int u = __float_as_uint(f);
    u += 0x7fffu + ((u >> 16) & 1u);   // round-to-nearest-even
    return (unsigned short)(u >> 16);
}

static __device__ __forceinline__ float sigmoid_f(float x) {
    return 1.0f / (1.0f + __expf(-x));
}
static __device__ __forceinline__ float tanh_f(float x) {
    float t = __expf(2.0f * x);
    return 1.0f - 2.0f / (t + 1.0f);   // saturates cleanly at +/-1 for large |x|
}

// ---------------------------------------------------------------------------
// Pass 0a: A = bf16(concat(x, h_prev)) -> [16384][1024], row-major
// ---------------------------------------------------------------------------
__global__ __launch_bounds__(256) void pack_a(const float* __restrict__ x,
                                              const float* __restrict__ hp,
                                              ushort_t* __restrict__ A) {
    int t = blockIdx.x * 256 + threadIdx.x;     // 2,097,152 threads, 8 elems each
    int row = t >> 7;                           // 128 chunks of 8 per row
    int kc = (t & 127) << 3;                    // k offset, multiple of 8
    const float* src = (kc < 512) ? (x + (size_t)row * 512 + kc)
                                  : (hp + (size_t)row * 512 + (kc - 512));
    float4 v0 = ((const float4*)src)[0];
    float4 v1 = ((const float4*)src)[1];
    ushort_t o[8] __attribute__((aligned(16)));
    o[0] = f2bf(v0.x); o[1] = f2bf(v0.y); o[2] = f2bf(v0.z); o[3] = f2bf(v0.w);
    o[4] = f2bf(v1.x); o[5] = f2bf(v1.y); o[6] = f2bf(v1.z); o[7] = f2bf(v1.w);
    *((uint4*)(A + (size_t)row * KDIM + kc)) = *((const uint4*)o);
}

// ---------------------------------------------------------------------------
// Pass 0b: Bt[n'][k] = bf16(Wcat[k][col]),  n' = 4*h + g,  col = g*512 + h
// Wcat rows 0..511 = W_i, rows 512..1023 = W_h.  Bt is [2048][1024].
// ---------------------------------------------------------------------------
__global__ __launch_bounds__(256) void pack_b(const float* __restrict__ Wi,
                                              const float* __restrict__ Wh,
                                              ushort_t* __restrict__ Bt) {
    int t = blockIdx.x * 256 + threadIdx.x;     // 262,144 threads, 8 elems each
    int np = t >> 7;                            // n' in [0, 2048)
    int kc = (t & 127) << 3;
    int col = ((np & 3) << 9) | (np >> 2);      // g*512 + h
    ushort_t o[8] __attribute__((aligned(16)));
#pragma unroll
    for (int j = 0; j < 8; ++j) {
        int k = kc + j;
        float v = (k < 512) ? Wi[(size_t)k * NDIM + col]
                            : Wh[(size_t)(k - 512) * NDIM + col];
        o[j] = f2bf(v);
    }
    *((uint4*)(Bt + (size_t)np * KDIM + kc)) = *((const uint4*)o);
}

// ---------------------------------------------------------------------------
// Pass 1: 128x128-tile bf16 MFMA GEMM over [M=16384,K=1024] x [N'=2048,K]^T
// with fused LSTM-cell epilogue (bias + activations + c/h computation).
// Writes c to c_out and pre-LN h to h_out.
// ---------------------------------------------------------------------------
__global__ __launch_bounds__(256) void gemm_cell(const ushort_t* __restrict__ A,
                                                 const ushort_t* __restrict__ Bt,
                                                 const float* __restrict__ b,
                                                 const float* __restrict__ c_prev,
                                                 float* __restrict__ h_out,
                                                 float* __restrict__ c_out) {
    __shared__ float smem_f[8192];                 // 32 KB, dual-purpose
    ushort_t* Als = (ushort_t*)smem_f;             // 128 rows x 64 k (bf16)
    ushort_t* Bls = Als + 128 * 64;                // 128 rows x 64 k (bf16)

    const int tid  = threadIdx.x;
    const int w    = tid >> 6;
    const int lane = tid & 63;
    const int m0 = blockIdx.x * 128;               // M tile
    const int n0 = blockIdx.y * 128;               // permuted-N tile
    const int wm = (w >> 1) * 64;                  // wave row offset in tile
    const int wn = (w & 1) * 64;                   // wave col offset in tile
    const int lr   = lane & 15;
    const int quad = lane >> 4;

    f32x4 zero = {0.f, 0.f, 0.f, 0.f};
    f32x4 acc[4][4];
#pragma unroll
    for (int i = 0; i < 4; ++i)
#pragma unroll
        for (int j = 0; j < 4; ++j) acc[i][j] = zero;

    for (int kt = 0; kt < KDIM / 64; ++kt) {
        // ---- stage A and Bt tiles via async global->LDS (16B chunks) ----
#pragma unroll
        for (int r = 0; r < 4; ++r) {
            int c = r * 256 + tid;                 // chunk id 0..1023
            int trow = c >> 3;                     // tile row 0..127
            int tk = (c & 7) << 3;                 // k offset within 64
            const ushort_t* ga = A + (size_t)(m0 + trow) * KDIM + kt * 64 + tk;
            __builtin_amdgcn_global_load_lds(
                (const __attribute__((address_space(1))) void*)ga,
                (__attribute__((address_space(3))) void*)((char*)Als + c * 16),
                16, 0, 0);
            const ushort_t* gb = Bt + (size_t)(n0 + trow) * KDIM + kt * 64 + tk;
            __builtin_amdgcn_global_load_lds(
                (const __attribute__((address_space(1))) void*)gb,
                (__attribute__((address_space(3))) void*)((char*)Bls + c * 16),
                16, 0, 0);
        }
        __syncthreads();

        // ---- MFMA over the 64-deep K tile (two 32-wide steps) ----
#pragma unroll
        for (int kk = 0; kk < 2; ++kk) {
            bf16x8 af[4], bf[4];
#pragma unroll
            for (int t2 = 0; t2 < 4; ++t2) {
                af[t2] = *((const bf16x8*)(Als + (wm + t2 * 16 + lr) * 64 + kk * 32 + quad * 8));
                bf[t2] = *((const bf16x8*)(Bls + (wn + t2 * 16 + lr) * 64 + kk * 32 + quad * 8));
            }
#pragma unroll
            for (int tm = 0; tm < 4; ++tm)
#pragma unroll
                for (int tn = 0; tn < 4; ++tn)
                    acc[tm][tn] = __builtin_amdgcn_mfma_f32_16x16x32_bf16(
                        af[tm], bf[tn], acc[tm][tn], 0, 0, 0);
        }
        __syncthreads();
    }

    // ---- fused epilogue: two 64-row halves through LDS ----
#pragma unroll
    for (int half = 0; half < 2; ++half) {
        __syncthreads();
        if ((w >> 1) == half) {
            // C/D layout: col = lane&15, row = quad*4 + reg (within 16x16 tile)
#pragma unroll
            for (int tm = 0; tm < 4; ++tm) {
                int rl = tm * 16 + quad * 4;
#pragma unroll
                for (int tn = 0; tn < 4; ++tn) {
                    int cl = wn + tn * 16 + lr;
#pragma unroll
                    for (int rg = 0; rg < 4; ++rg)
                        smem_f[(rl + rg) * 128 + cl] = acc[tm][tn][rg];
                }
            }
        }
        __syncthreads();
        // 64 rows x 32 h-indices; 4 adjacent cols (n'=4h+g) = the 4 gates
#pragma unroll
        for (int ii = 0; ii < 8; ++ii) {
            int item = ii * 256 + tid;
            int rloc = item >> 5;
            int hloc = item & 31;
            float4 gv = *((const float4*)(smem_f + rloc * 128 + hloc * 4));
            int grow = m0 + half * 64 + rloc;
            int hg = (n0 >> 2) + hloc;
            float iv = sigmoid_f(gv.x + b[hg]);
            float fv = sigmoid_f(gv.y + b[512 + hg]);
            float g2 = tanh_f(gv.z + b[1024 + hg]);
            float ov = sigmoid_f(gv.w + b[1536 + hg]);
            float cp = c_prev[(size_t)grow * HDIM + hg];
            float cn = fv * cp + iv * g2;
            float hr = ov * tanh_f(cn);
            c_out[(size_t)grow * HDIM + hg] = cn;
            h_out[(size_t)grow * HDIM + hg] = hr;
        }
    }
}

// ---------------------------------------------------------------------------
// Pass 2: in-place row-wise LayerNorm on h (one wave per 512-elem row)
// ---------------------------------------------------------------------------
__global__ __launch_bounds__(256) void ln_kernel(float* __restrict__ h,
                                                 const float* __restrict__ lw,
                                                 const float* __restrict__ lb) {
    int w = threadIdx.x >> 6;
    int lane = threadIdx.x & 63;
    int row = blockIdx.x * 4 + w;
    float* p = h + (size_t)row * HDIM + lane * 8;
    float4 a = ((const float4*)p)[0];
    float4 c = ((const float4*)p)[1];
    float s  = a.x + a.y + a.z + a.w + c.x + c.y + c.z + c.w;
    float ss = a.x * a.x + a.y * a.y + a.z * a.z + a.w * a.w +
               c.x * c.x + c.y * c.y + c.z * c.z + c.w * c.w;
#pragma unroll
    for (int off = 32; off > 0; off >>= 1) {
        s  += __shfl_xor(s, off);
        ss += __shfl_xor(ss, off);
    }
    float mu = s * (1.0f / 512.0f);
    float var = ss * (1.0f / 512.0f) - mu * mu;
    float rstd = rsqrtf(var + 1e-5f);
    const float* wp = lw + lane * 8;
    const float* bp = lb + lane * 8;
    float4 w0 = ((const float4*)wp)[0];
    float4 w1 = ((const float4*)wp)[1];
    float4 b0 = ((const float4*)bp)[0];
    float4 b1 = ((const float4*)bp)[1];
    a.x = (a.x - mu) * rstd * w0.x + b0.x;
    a.y = (a.y - mu) * rstd * w0.y + b0.y;
    a.z = (a.z - mu) * rstd * w0.z + b0.z;
    a.w = (a.w - mu) * rstd * w0.w + b0.w;
    c.x = (c.x - mu) * rstd * w1.x + b1.x;
    c.y = (c.y - mu) * rstd * w1.y + b1.y;
    c.z = (c.z - mu) * rstd * w1.z + b1.z;
    c.w = (c.w - mu) * rstd * w1.w + b1.w;
    ((float4*)p)[0] = a;
    ((float4*)p)[1] = c;
}

extern "C" void kernel_launch(void* const* d_in, const int* in_sizes, int n_in,
                              void* d_out, int out_size, void* d_ws, size_t ws_size,
                              hipStream_t stream) {
    const float* x      = (const float*)d_in[0];
    const float* h_prev = (const float*)d_in[1];
    const float* c_prev = (const float*)d_in[2];
    const float* W_i    = (const float*)d_in[3];
    const float* W_h    = (const float*)d_in[4];
    const float* b      = (const float*)d_in[5];
    const float* ln_w   = (const float*)d_in[6];
    const float* ln_b   = (const float*)d_in[7];

    float* h_out = (float*)d_out;                       // [16384][512]
    float* c_out = h_out + (size_t)MROWS * HDIM;        // [16384][512]

    ushort_t* A  = (ushort_t*)d_ws;                     // 32 MB
    ushort_t* Bt = A + (size_t)MROWS * KDIM;            // 4 MB

    pack_a<<<8192, 256, 0, stream>>>(x, h_prev, A);
    pack_b<<<1024, 256, 0, stream>>>(W_i, W_h, Bt);
    dim3 grid(MROWS / 128, NDIM / 128);
    gemm_cell<<<grid, 256, 0, stream>>>(A, Bt, b, c_prev, h_out, c_out);
    ln_kernel<<<MROWS / 4, 256, 0, stream>>>(h_out, ln_w, ln_b);
}

// Round 2
// 285.966 us; speedup vs baseline: 1.0874x; 1.0874x over previous
//
#include <hip/hip_runtime.h>
#include <cstdint>
#include <cstddef>

typedef unsigned short ushort_t;
typedef __attribute__((ext_vector_type(8))) short bf16x8;
typedef __attribute__((ext_vector_type(4))) float f32x4;

#define MROWS 16384
#define KDIM  1024
#define NDIM  2048
#define HDIM  512

static __device__ __forceinline__ unsigned short f2bf(float f) {
    unsigned int u = __float_as_uint(f);
    u += 0x7fffu + ((u >> 16) & 1u);   // round-to-nearest-even
    return (unsigned short)(u >> 16);
}

static __device__ __forceinline__ float sigmoid_f(float x) {
    return 1.0f / (1.0f + __expf(-x));
}
static __device__ __forceinline__ float tanh_f(float x) {
    float t = __expf(2.0f * x);
    return 1.0f - 2.0f / (t + 1.0f);   // saturates cleanly at +/-1 for large |x|
}

// ---------------------------------------------------------------------------
// Pass 0 (merged): blocks [0,8192): A = bf16(concat(x,h_prev)) [16384][1024]
//                  blocks [8192,8704): Bt via LDS transpose
//                  Bt[n'][k] = bf16(Wcat[k][col]), n' = 4h+g, col = g*512+h
// ---------------------------------------------------------------------------
__global__ __launch_bounds__(256) void pack_ab(const float* __restrict__ x,
                                               const float* __restrict__ hp,
                                               const float* __restrict__ Wi,
                                               const float* __restrict__ Wh,
                                               ushort_t* __restrict__ A,
                                               ushort_t* __restrict__ Bt) {
    __shared__ ushort_t sm[64][72];                 // pack_b transpose tile (+8 pad)
    const int tid = threadIdx.x;
    if (blockIdx.x < 8192) {
        int t = blockIdx.x * 256 + tid;             // 8 elems per thread
        int row = t >> 7;
        int kc = (t & 127) << 3;                    // wave-uniform x vs hp branch
        const float* src = (kc < 512) ? (x + (size_t)row * 512 + kc)
                                      : (hp + (size_t)row * 512 + (kc - 512));
        float4 v0 = ((const float4*)src)[0];
        float4 v1 = ((const float4*)src)[1];
        ushort_t o[8] __attribute__((aligned(16)));
        o[0] = f2bf(v0.x); o[1] = f2bf(v0.y); o[2] = f2bf(v0.z); o[3] = f2bf(v0.w);
        o[4] = f2bf(v1.x); o[5] = f2bf(v1.y); o[6] = f2bf(v1.z); o[7] = f2bf(v1.w);
        *((uint4*)(A + (size_t)row * KDIM + kc)) = *((const uint4*)o);
    } else {
        int b2 = blockIdx.x - 8192;                 // 0..511
        int kt = b2 >> 5;                           // k-tile 0..15 (64 rows each)
        int ct = b2 & 31;                           // col-tile 0..31 (64 cols each)
        const float* W = (kt < 8) ? (Wi + (size_t)(kt * 64) * NDIM)
                                  : (Wh + (size_t)((kt - 8) * 64) * NDIM);
        // coalesced 64x64 fp32 tile load -> bf16 LDS
        int c0 = (tid & 15) * 4;
        int r0 = tid >> 4;                          // 0..15
#pragma unroll
        for (int r = 0; r < 4; ++r) {
            int krow = r * 16 + r0;
            float4 v = *((const float4*)(W + (size_t)krow * NDIM + ct * 64 + c0));
            sm[krow][c0 + 0] = f2bf(v.x);
            sm[krow][c0 + 1] = f2bf(v.y);
            sm[krow][c0 + 2] = f2bf(v.z);
            sm[krow][c0 + 3] = f2bf(v.w);
        }
        __syncthreads();
        int g = (ct * 64) >> 9;                     // gate 0..3 (tile never spans g)
        int h0 = ct * 64 - g * 512;
#pragma unroll
        for (int q = tid; q < 512; q += 256) {
            int cc = q >> 3;                        // col within tile
            int kc = (q & 7) * 8;                   // k chunk within tile
            ushort_t o[8] __attribute__((aligned(16)));
#pragma unroll
            for (int j = 0; j < 8; ++j) o[j] = sm[kc + j][cc];
            int np = 4 * (h0 + cc) + g;
            *((uint4*)(Bt + (size_t)np * KDIM + kt * 64 + kc)) = *((const uint4*)o);
        }
    }
}

// ---------------------------------------------------------------------------
// Pass 1: 128x128-tile bf16 MFMA GEMM [M=16384,K=1024] x [N'=2048,K]^T
// XOR-swizzled LDS staging (conflict-free b128 fragment reads) + fused
// LSTM-cell epilogue. grid.x = n-tile (A-tile L2 reuse across adjacent blocks)
// ---------------------------------------------------------------------------
__global__ __launch_bounds__(256) void gemm_cell(const ushort_t* __restrict__ A,
                                                 const ushort_t* __restrict__ Bt,
                                                 const float* __restrict__ b,
                                                 const float* __restrict__ c_prev,
                                                 float* __restrict__ h_out,
                                                 float* __restrict__ c_out) {
    __shared__ float smem_f[8192];                 // 32 KB, dual-purpose
    ushort_t* Als = (ushort_t*)smem_f;             // 128 rows x 8 chunks x 8 bf16
    ushort_t* Bls = Als + 128 * 64;

    const int tid  = threadIdx.x;
    const int w    = tid >> 6;
    const int lane = tid & 63;
    const int n0 = blockIdx.x * 128;               // permuted-N tile
    const int m0 = blockIdx.y * 128;               // M tile
    const int wm = (w >> 1) * 64;
    const int wn = (w & 1) * 64;
    const int lr   = lane & 15;
    const int quad = lane >> 4;
    const int sw   = lr & 7;                       // per-lane read swizzle key

    f32x4 zero = {0.f, 0.f, 0.f, 0.f};
    f32x4 acc[4][4];
#pragma unroll
    for (int i = 0; i < 4; ++i)
#pragma unroll
        for (int j = 0; j < 4; ++j) acc[i][j] = zero;

    for (int kt = 0; kt < KDIM / 64; ++kt) {
        // stage A/B tiles; LDS slot (row, ch) holds global chunk (row, ch^(row&7))
#pragma unroll
        for (int r = 0; r < 4; ++r) {
            int c = r * 256 + tid;                 // LDS slot id, lane-contiguous
            int trow = c >> 3;
            int chg = (c & 7) ^ (trow & 7);        // swizzled global chunk
            const ushort_t* ga = A + (size_t)(m0 + trow) * KDIM + kt * 64 + chg * 8;
            __builtin_amdgcn_global_load_lds(
                (const __attribute__((address_space(1))) void*)ga,
                (__attribute__((address_space(3))) void*)((char*)Als + c * 16),
                16, 0, 0);
            const ushort_t* gb = Bt + (size_t)(n0 + trow) * KDIM + kt * 64 + chg * 8;
            __builtin_amdgcn_global_load_lds(
                (const __attribute__((address_space(1))) void*)gb,
                (__attribute__((address_space(3))) void*)((char*)Bls + c * 16),
                16, 0, 0);
        }
        __syncthreads();

#pragma unroll
        for (int kk = 0; kk < 2; ++kk) {
            bf16x8 af[4], bf[4];
#pragma unroll
            for (int t2 = 0; t2 < 4; ++t2) {
                int ra = wm + t2 * 16 + lr;
                int rb = wn + t2 * 16 + lr;
                int ch = kk * 4 + quad;
                af[t2] = *((const bf16x8*)(Als + (ra * 8 + (ch ^ sw)) * 8));
                bf[t2] = *((const bf16x8*)(Bls + (rb * 8 + (ch ^ sw)) * 8));
            }
#pragma unroll
            for (int tm = 0; tm < 4; ++tm)
#pragma unroll
                for (int tn = 0; tn < 4; ++tn)
                    acc[tm][tn] = __builtin_amdgcn_mfma_f32_16x16x32_bf16(
                        af[tm], bf[tn], acc[tm][tn], 0, 0, 0);
        }
        __syncthreads();
    }

    // ---- fused epilogue: two 64-row halves through LDS ----
#pragma unroll
    for (int half = 0; half < 2; ++half) {
        __syncthreads();
        if ((w >> 1) == half) {
            // C/D: col = lane&15, row = quad*4 + reg (within each 16x16 tile)
#pragma unroll
            for (int tm = 0; tm < 4; ++tm) {
                int rl = tm * 16 + quad * 4;
#pragma unroll
                for (int tn = 0; tn < 4; ++tn) {
                    int cl = wn + tn * 16 + lr;
#pragma unroll
                    for (int rg = 0; rg < 4; ++rg)
                        smem_f[(rl + rg) * 128 + cl] = acc[tm][tn][rg];
                }
            }
        }
        __syncthreads();
        // 64 rows x 32 h; 4 adjacent cols (n'=4h+g) = the 4 gates of one h
#pragma unroll
        for (int ii = 0; ii < 8; ++ii) {
            int item = ii * 256 + tid;
            int rloc = item >> 5;
            int hloc = item & 31;
            float4 gv = *((const float4*)(smem_f + rloc * 128 + hloc * 4));
            int grow = m0 + half * 64 + rloc;
            int hg = (n0 >> 2) + hloc;
            float iv = sigmoid_f(gv.x + b[hg]);
            float fv = sigmoid_f(gv.y + b[512 + hg]);
            float g2 = tanh_f(gv.z + b[1024 + hg]);
            float ov = sigmoid_f(gv.w + b[1536 + hg]);
            float cp = c_prev[(size_t)grow * HDIM + hg];
            float cn = fv * cp + iv * g2;
            float hr = ov * tanh_f(cn);
            c_out[(size_t)grow * HDIM + hg] = cn;
            h_out[(size_t)grow * HDIM + hg] = hr;
        }
    }
}

// ---------------------------------------------------------------------------
// Pass 2: in-place row-wise LayerNorm on h (one wave per 512-elem row)
// ---------------------------------------------------------------------------
__global__ __launch_bounds__(256) void ln_kernel(float* __restrict__ h,
                                                 const float* __restrict__ lw,
                                                 const float* __restrict__ lb) {
    int w = threadIdx.x >> 6;
    int lane = threadIdx.x & 63;
    int row = blockIdx.x * 4 + w;
    float* p = h + (size_t)row * HDIM + lane * 8;
    float4 a = ((const float4*)p)[0];
    float4 c = ((const float4*)p)[1];
    float s  = a.x + a.y + a.z + a.w + c.x + c.y + c.z + c.w;
    float ss = a.x * a.x + a.y * a.y + a.z * a.z + a.w * a.w +
               c.x * c.x + c.y * c.y + c.z * c.z + c.w * c.w;
#pragma unroll
    for (int off = 32; off > 0; off >>= 1) {
        s  += __shfl_xor(s, off);
        ss += __shfl_xor(ss, off);
    }
    float mu = s * (1.0f / 512.0f);
    float var = ss * (1.0f / 512.0f) - mu * mu;
    float rstd = rsqrtf(var + 1e-5f);
    const float* wp = lw + lane * 8;
    const float* bp = lb + lane * 8;
    float4 w0 = ((const float4*)wp)[0];
    float4 w1 = ((const float4*)wp)[1];
    float4 b0 = ((const float4*)bp)[0];
    float4 b1 = ((const float4*)bp)[1];
    a.x = (a.x - mu) * rstd * w0.x + b0.x;
    a.y = (a.y - mu) * rstd * w0.y + b0.y;
    a.z = (a.z - mu) * rstd * w0.z + b0.z;
    a.w = (a.w - mu) * rstd * w0.w + b0.w;
    c.x = (c.x - mu) * rstd * w1.x + b1.x;
    c.y = (c.y - mu) * rstd * w1.y + b1.y;
    c.z = (c.z - mu) * rstd * w1.z + b1.z;
    c.w = (c.w - mu) * rstd * w1.w + b1.w;
    ((float4*)p)[0] = a;
    ((float4*)p)[1] = c;
}

extern "C" void kernel_launch(void* const* d_in, const int* in_sizes, int n_in,
                              void* d_out, int out_size, void* d_ws, size_t ws_size,
                              hipStream_t stream) {
    const float* x      = (const float*)d_in[0];
    const float* h_prev = (const float*)d_in[1];
    const float* c_prev = (const float*)d_in[2];
    const float* W_i    = (const float*)d_in[3];
    const float* W_h    = (const float*)d_in[4];
    const float* b      = (const float*)d_in[5];
    const float* ln_w   = (const float*)d_in[6];
    const float* ln_b   = (const float*)d_in[7];

    float* h_out = (float*)d_out;                       // [16384][512]
    float* c_out = h_out + (size_t)MROWS * HDIM;        // [16384][512]

    ushort_t* A  = (ushort_t*)d_ws;                     // 32 MB
    ushort_t* Bt = A + (size_t)MROWS * KDIM;            // 4 MB

    pack_ab<<<8192 + 512, 256, 0, stream>>>(x, h_prev, W_i, W_h, A, Bt);
    dim3 grid(NDIM / 128, MROWS / 128);
    gemm_cell<<<grid, 256, 0, stream>>>(A, Bt, b, c_prev, h_out, c_out);
    ln_kernel<<<MROWS / 4, 256, 0, stream>>>(h_out, ln_w, ln_b);
}

// Round 3
// 256.961 us; speedup vs baseline: 1.2102x; 1.1129x over previous
//
#include <hip/hip_runtime.h>
#include <cstdint>
#include <cstddef>

typedef unsigned short ushort_t;
typedef __attribute__((ext_vector_type(8))) short bf16x8;
typedef __attribute__((ext_vector_type(4))) float f32x4;

#define MROWS 16384
#define KDIM  1024
#define NDIM  2048
#define HDIM  512

static __device__ __forceinline__ unsigned short f2bf(float f) {
    unsigned int u = __float_as_uint(f);
    u += 0x7fffu + ((u >> 16) & 1u);   // round-to-nearest-even
    return (unsigned short)(u >> 16);
}

static __device__ __forceinline__ float sigmoid_f(float x) {
    return 1.0f / (1.0f + __expf(-x));
}
static __device__ __forceinline__ float tanh_f(float x) {
    float t = __expf(2.0f * x);
    return 1.0f - 2.0f / (t + 1.0f);   // saturates cleanly at +/-1 for large |x|
}

// ---------------------------------------------------------------------------
// Pass 0 (merged): blocks [0,8192): A = bf16(concat(x,h_prev)) [16384][1024]
//                  blocks [8192,8704): Bt via LDS transpose
//                  Bt[n'][k] = bf16(Wcat[k][col]), n' = 4h+g, col = g*512+h
// ---------------------------------------------------------------------------
__global__ __launch_bounds__(256) void pack_ab(const float* __restrict__ x,
                                               const float* __restrict__ hp,
                                               const float* __restrict__ Wi,
                                               const float* __restrict__ Wh,
                                               ushort_t* __restrict__ A,
                                               ushort_t* __restrict__ Bt) {
    __shared__ ushort_t sm[64][72];                 // pack_b transpose tile (+8 pad)
    const int tid = threadIdx.x;
    if (blockIdx.x < 8192) {
        int t = blockIdx.x * 256 + tid;             // 8 elems per thread
        int row = t >> 7;
        int kc = (t & 127) << 3;                    // wave-uniform x vs hp branch
        const float* src = (kc < 512) ? (x + (size_t)row * 512 + kc)
                                      : (hp + (size_t)row * 512 + (kc - 512));
        float4 v0 = ((const float4*)src)[0];
        float4 v1 = ((const float4*)src)[1];
        ushort_t o[8] __attribute__((aligned(16)));
        o[0] = f2bf(v0.x); o[1] = f2bf(v0.y); o[2] = f2bf(v0.z); o[3] = f2bf(v0.w);
        o[4] = f2bf(v1.x); o[5] = f2bf(v1.y); o[6] = f2bf(v1.z); o[7] = f2bf(v1.w);
        *((uint4*)(A + (size_t)row * KDIM + kc)) = *((const uint4*)o);
    } else {
        int b2 = blockIdx.x - 8192;                 // 0..511
        int kt = b2 >> 5;                           // k-tile 0..15 (64 rows each)
        int ct = b2 & 31;                           // col-tile 0..31 (64 cols each)
        const float* W = (kt < 8) ? (Wi + (size_t)(kt * 64) * NDIM)
                                  : (Wh + (size_t)((kt - 8) * 64) * NDIM);
        // coalesced 64x64 fp32 tile load -> bf16 LDS
        int c0 = (tid & 15) * 4;
        int r0 = tid >> 4;                          // 0..15
#pragma unroll
        for (int r = 0; r < 4; ++r) {
            int krow = r * 16 + r0;
            float4 v = *((const float4*)(W + (size_t)krow * NDIM + ct * 64 + c0));
            sm[krow][c0 + 0] = f2bf(v.x);
            sm[krow][c0 + 1] = f2bf(v.y);
            sm[krow][c0 + 2] = f2bf(v.z);
            sm[krow][c0 + 3] = f2bf(v.w);
        }
        __syncthreads();
        int g = (ct * 64) >> 9;                     // gate 0..3 (tile never spans g)
        int h0 = ct * 64 - g * 512;
#pragma unroll
        for (int q = tid; q < 512; q += 256) {
            int cc = q >> 3;                        // col within tile
            int kc = (q & 7) * 8;                   // k chunk within tile
            ushort_t o[8] __attribute__((aligned(16)));
#pragma unroll
            for (int j = 0; j < 8; ++j) o[j] = sm[kc + j][cc];
            int np = 4 * (h0 + cc) + g;
            *((uint4*)(Bt + (size_t)np * KDIM + kt * 64 + kc)) = *((const uint4*)o);
        }
    }
}

// ---------------------------------------------------------------------------
// Pass 1: 128x64-tile bf16 MFMA GEMM [M=16384,K=1024] x [N'=2048,K]^T.
// Wave tile 64x32 (acc = 32 regs, 4-blocks/CU occupancy target).
// XOR-swizzled LDS staging; barrier-free per-wave-private-scratch epilogue
// with fused LSTM-cell math. 1-D grid, XCD-aware block swizzle.
// ---------------------------------------------------------------------------
__global__ __launch_bounds__(256, 4) void gemm_cell(const ushort_t* __restrict__ A,
                                                    const ushort_t* __restrict__ Bt,
                                                    const float* __restrict__ b,
                                                    const float* __restrict__ c_prev,
                                                    float* __restrict__ h_out,
                                                    float* __restrict__ c_out) {
    __shared__ float smem_f[6144];                 // 24 KB
    ushort_t* Als = (ushort_t*)smem_f;             // 128 rows x 64 k (16 KB)
    ushort_t* Bls = Als + 128 * 64;                //  64 rows x 64 k ( 8 KB)

    const int tid  = threadIdx.x;
    const int w    = tid >> 6;
    const int lane = tid & 63;
    // XCD-aware swizzle: each XCD's contiguous lid range shares A-tiles
    int bid = blockIdx.x;                          // 4096 blocks
    int lid = (bid >> 3) + (bid & 7) * 512;
    const int m0 = (lid >> 5) * 128;               // 128 m-tiles
    const int n0 = (lid & 31) * 64;                // 32 n-tiles (permuted N)
    const int wm = (w >> 1) * 64;                  // wave row offset
    const int wn = (w & 1) * 32;                   // wave col offset
    const int lr   = lane & 15;
    const int quad = lane >> 4;
    const int sw   = lr & 7;                       // read-side swizzle key

    f32x4 zero = {0.f, 0.f, 0.f, 0.f};
    f32x4 acc[4][2];
#pragma unroll
    for (int i = 0; i < 4; ++i)
#pragma unroll
        for (int j = 0; j < 2; ++j) acc[i][j] = zero;

    for (int kt = 0; kt < KDIM / 64; ++kt) {
        // stage tiles; LDS slot (row, ch) holds global chunk (row, ch^(row&7))
#pragma unroll
        for (int r = 0; r < 4; ++r) {              // A: slots 0..1023
            int c = r * 256 + tid;
            int trow = c >> 3;
            int chg = (c & 7) ^ (trow & 7);
            const ushort_t* ga = A + (size_t)(m0 + trow) * KDIM + kt * 64 + chg * 8;
            __builtin_amdgcn_global_load_lds(
                (const __attribute__((address_space(1))) void*)ga,
                (__attribute__((address_space(3))) void*)((char*)Als + c * 16),
                16, 0, 0);
        }
#pragma unroll
        for (int r = 0; r < 2; ++r) {              // B: slots 0..511
            int c = r * 256 + tid;
            int trow = c >> 3;
            int chg = (c & 7) ^ (trow & 7);
            const ushort_t* gb = Bt + (size_t)(n0 + trow) * KDIM + kt * 64 + chg * 8;
            __builtin_amdgcn_global_load_lds(
                (const __attribute__((address_space(1))) void*)gb,
                (__attribute__((address_space(3))) void*)((char*)Bls + c * 16),
                16, 0, 0);
        }
        __syncthreads();

#pragma unroll
        for (int kk = 0; kk < 2; ++kk) {
            bf16x8 af[4], bf[2];
            int ch = kk * 4 + quad;
#pragma unroll
            for (int t2 = 0; t2 < 4; ++t2) {
                int ra = wm + t2 * 16 + lr;        // ra&7 == lr&7
                af[t2] = *((const bf16x8*)(Als + (ra * 8 + (ch ^ sw)) * 8));
            }
#pragma unroll
            for (int t2 = 0; t2 < 2; ++t2) {
                int rb = wn + t2 * 16 + lr;        // rb&7 == lr&7
                bf[t2] = *((const bf16x8*)(Bls + (rb * 8 + (ch ^ sw)) * 8));
            }
#pragma unroll
            for (int tm = 0; tm < 4; ++tm)
#pragma unroll
                for (int tn = 0; tn < 2; ++tn)
                    acc[tm][tn] = __builtin_amdgcn_mfma_f32_16x16x32_bf16(
                        af[tm], bf[tn], acc[tm][tn], 0, 0, 0);
        }
        __syncthreads();
    }
    // final loop barrier: all fragment reads done; LDS reusable, no extra sync

    // ---- barrier-free epilogue: per-wave private 4 KB scratch ----
    float* scr = smem_f + w * 1024;                // 32 rows x 32 cols per chunk
    const int hg0 = ((n0 + wn) >> 2) + ((lane & 1) << 2);   // 4 h-groups per lane
    const float4 bi4 = *((const float4*)(b + hg0));
    const float4 bf4 = *((const float4*)(b + 512 + hg0));
    const float4 bg4 = *((const float4*)(b + 1024 + hg0));
    const float4 bo4 = *((const float4*)(b + 1536 + hg0));
    const int rr = lane >> 1;                      // row within 32-row chunk

#pragma unroll
    for (int chunk = 0; chunk < 2; ++chunk) {
        // write acc (2 m-tiles = 32 rows x 32 cols), 16B-block XOR swizzle
#pragma unroll
        for (int tm2 = 0; tm2 < 2; ++tm2) {
            int tm = chunk * 2 + tm2;
#pragma unroll
            for (int tn = 0; tn < 2; ++tn) {
                int c = tn * 16 + lr;
#pragma unroll
                for (int rg = 0; rg < 4; ++rg) {
                    int r = tm2 * 16 + quad * 4 + rg;
                    int blk = (c >> 2) ^ (r & 7);
                    scr[r * 32 + blk * 4 + (c & 3)] = acc[tm][tn][rg];
                }
            }
        }
        // same-wave in-order DS pipe: no barrier needed
        float4 gv[4];
#pragma unroll
        for (int j = 0; j < 4; ++j) {
            int hg_l = ((lane & 1) << 2) + j;
            int blk = hg_l ^ (rr & 7);
            gv[j] = *((const float4*)(scr + rr * 32 + blk * 4));
        }
        int grow = m0 + wm + chunk * 32 + rr;
        float4 cp = *((const float4*)(c_prev + (size_t)grow * HDIM + hg0));
        float cn[4], hv[4];
        {
            float iv, fv, g2, ov;
            iv = sigmoid_f(gv[0].x + bi4.x); fv = sigmoid_f(gv[0].y + bf4.x);
            g2 = tanh_f(gv[0].z + bg4.x);    ov = sigmoid_f(gv[0].w + bo4.x);
            cn[0] = fv * cp.x + iv * g2;     hv[0] = ov * tanh_f(cn[0]);
            iv = sigmoid_f(gv[1].x + bi4.y); fv = sigmoid_f(gv[1].y + bf4.y);
            g2 = tanh_f(gv[1].z + bg4.y);    ov = sigmoid_f(gv[1].w + bo4.y);
            cn[1] = fv * cp.y + iv * g2;     hv[1] = ov * tanh_f(cn[1]);
            iv = sigmoid_f(gv[2].x + bi4.z); fv = sigmoid_f(gv[2].y + bf4.z);
            g2 = tanh_f(gv[2].z + bg4.z);    ov = sigmoid_f(gv[2].w + bo4.z);
            cn[2] = fv * cp.z + iv * g2;     hv[2] = ov * tanh_f(cn[2]);
            iv = sigmoid_f(gv[3].x + bi4.w); fv = sigmoid_f(gv[3].y + bf4.w);
            g2 = tanh_f(gv[3].z + bg4.w);    ov = sigmoid_f(gv[3].w + bo4.w);
            cn[3] = fv * cp.w + iv * g2;     hv[3] = ov * tanh_f(cn[3]);
        }
        float4 cno = {cn[0], cn[1], cn[2], cn[3]};
        float4 hvo = {hv[0], hv[1], hv[2], hv[3]};
        *((float4*)(c_out + (size_t)grow * HDIM + hg0)) = cno;
        *((float4*)(h_out + (size_t)grow * HDIM + hg0)) = hvo;
    }
}

// ---------------------------------------------------------------------------
// Pass 2: in-place row-wise LayerNorm on h (one wave per 512-elem row)
// ---------------------------------------------------------------------------
__global__ __launch_bounds__(256) void ln_kernel(float* __restrict__ h,
                                                 const float* __restrict__ lw,
                                                 const float* __restrict__ lb) {
    int w = threadIdx.x >> 6;
    int lane = threadIdx.x & 63;
    int row = blockIdx.x * 4 + w;
    float* p = h + (size_t)row * HDIM + lane * 8;
    float4 a = ((const float4*)p)[0];
    float4 c = ((const float4*)p)[1];
    float s  = a.x + a.y + a.z + a.w + c.x + c.y + c.z + c.w;
    float ss = a.x * a.x + a.y * a.y + a.z * a.z + a.w * a.w +
               c.x * c.x + c.y * c.y + c.z * c.z + c.w * c.w;
#pragma unroll
    for (int off = 32; off > 0; off >>= 1) {
        s  += __shfl_xor(s, off);
        ss += __shfl_xor(ss, off);
    }
    float mu = s * (1.0f / 512.0f);
    float var = ss * (1.0f / 512.0f) - mu * mu;
    float rstd = rsqrtf(var + 1e-5f);
    const float* wp = lw + lane * 8;
    const float* bp = lb + lane * 8;
    float4 w0 = ((const float4*)wp)[0];
    float4 w1 = ((const float4*)wp)[1];
    float4 b0 = ((const float4*)bp)[0];
    float4 b1 = ((const float4*)bp)[1];
    a.x = (a.x - mu) * rstd * w0.x + b0.x;
    a.y = (a.y - mu) * rstd * w0.y + b0.y;
    a.z = (a.z - mu) * rstd * w0.z + b0.z;
    a.w = (a.w - mu) * rstd * w0.w + b0.w;
    c.x = (c.x - mu) * rstd * w1.x + b1.x;
    c.y = (c.y - mu) * rstd * w1.y + b1.y;
    c.z = (c.z - mu) * rstd * w1.z + b1.z;
    c.w = (c.w - mu) * rstd * w1.w + b1.w;
    ((float4*)p)[0] = a;
    ((float4*)p)[1] = c;
}

extern "C" void kernel_launch(void* const* d_in, const int* in_sizes, int n_in,
                              void* d_out, int out_size, void* d_ws, size_t ws_size,
                              hipStream_t stream) {
    const float* x      = (const float*)d_in[0];
    const float* h_prev = (const float*)d_in[1];
    const float* c_prev = (const float*)d_in[2];
    const float* W_i    = (const float*)d_in[3];
    const float* W_h    = (const float*)d_in[4];
    const float* b      = (const float*)d_in[5];
    const float* ln_w   = (const float*)d_in[6];
    const float* ln_b   = (const float*)d_in[7];

    float* h_out = (float*)d_out;                       // [16384][512]
    float* c_out = h_out + (size_t)MROWS * HDIM;        // [16384][512]

    ushort_t* A  = (ushort_t*)d_ws;                     // 32 MB
    ushort_t* Bt = A + (size_t)MROWS * KDIM;            // 4 MB

    pack_ab<<<8192 + 512, 256, 0, stream>>>(x, h_prev, W_i, W_h, A, Bt);
    gemm_cell<<<4096, 256, 0, stream>>>(A, Bt, b, c_prev, h_out, c_out);
    ln_kernel<<<MROWS / 4, 256, 0, stream>>>(h_out, ln_w, ln_b);
}

// Round 4
// 254.808 us; speedup vs baseline: 1.2204x; 1.0085x over previous
//
#include <hip/hip_runtime.h>
#include <cstdint>
#include <cstddef>

typedef unsigned short ushort_t;
typedef __attribute__((ext_vector_type(8))) short bf16x8;
typedef __attribute__((ext_vector_type(4))) float f32x4;

#define MROWS 16384
#define KDIM  1024
#define NDIM  2048
#define HDIM  512

static __device__ __forceinline__ unsigned short f2bf(float f) {
    unsigned int u = __float_as_uint(f);
    u += 0x7fffu + ((u >> 16) & 1u);   // round-to-nearest-even
    return (unsigned short)(u >> 16);
}

static __device__ __forceinline__ float sigmoid_f(float x) {
    return 1.0f / (1.0f + __expf(-x));
}
static __device__ __forceinline__ float tanh_f(float x) {
    float t = __expf(2.0f * x);
    return 1.0f - 2.0f / (t + 1.0f);   // saturates cleanly at +/-1 for large |x|
}

// ---------------------------------------------------------------------------
// Pass 0 (merged): blocks [0,8192): A = bf16(concat(x,h_prev)) [16384][1024]
//                  blocks [8192,8704): Bt via LDS transpose
//                  Bt[n'][k] = bf16(Wcat[k][col]), n' = 4h+g, col = g*512+h
// ---------------------------------------------------------------------------
__global__ __launch_bounds__(256) void pack_ab(const float* __restrict__ x,
                                               const float* __restrict__ hp,
                                               const float* __restrict__ Wi,
                                               const float* __restrict__ Wh,
                                               ushort_t* __restrict__ A,
                                               ushort_t* __restrict__ Bt) {
    __shared__ ushort_t sm[64][72];                 // pack_b transpose tile (+8 pad)
    const int tid = threadIdx.x;
    if (blockIdx.x < 8192) {
        int t = blockIdx.x * 256 + tid;             // 8 elems per thread
        int row = t >> 7;
        int kc = (t & 127) << 3;                    // wave-uniform x vs hp branch
        const float* src = (kc < 512) ? (x + (size_t)row * 512 + kc)
                                      : (hp + (size_t)row * 512 + (kc - 512));
        float4 v0 = ((const float4*)src)[0];
        float4 v1 = ((const float4*)src)[1];
        ushort_t o[8] __attribute__((aligned(16)));
        o[0] = f2bf(v0.x); o[1] = f2bf(v0.y); o[2] = f2bf(v0.z); o[3] = f2bf(v0.w);
        o[4] = f2bf(v1.x); o[5] = f2bf(v1.y); o[6] = f2bf(v1.z); o[7] = f2bf(v1.w);
        *((uint4*)(A + (size_t)row * KDIM + kc)) = *((const uint4*)o);
    } else {
        int b2 = blockIdx.x - 8192;                 // 0..511
        int kt = b2 >> 5;                           // k-tile 0..15 (64 rows each)
        int ct = b2 & 31;                           // col-tile 0..31 (64 cols each)
        const float* W = (kt < 8) ? (Wi + (size_t)(kt * 64) * NDIM)
                                  : (Wh + (size_t)((kt - 8) * 64) * NDIM);
        // coalesced 64x64 fp32 tile load -> bf16 LDS
        int c0 = (tid & 15) * 4;
        int r0 = tid >> 4;                          // 0..15
#pragma unroll
        for (int r = 0; r < 4; ++r) {
            int krow = r * 16 + r0;
            float4 v = *((const float4*)(W + (size_t)krow * NDIM + ct * 64 + c0));
            sm[krow][c0 + 0] = f2bf(v.x);
            sm[krow][c0 + 1] = f2bf(v.y);
            sm[krow][c0 + 2] = f2bf(v.z);
            sm[krow][c0 + 3] = f2bf(v.w);
        }
        __syncthreads();
        int g = (ct * 64) >> 9;                     // gate 0..3 (tile never spans g)
        int h0 = ct * 64 - g * 512;
#pragma unroll
        for (int q = tid; q < 512; q += 256) {
            int cc = q >> 3;                        // col within tile
            int kc = (q & 7) * 8;                   // k chunk within tile
            ushort_t o[8] __attribute__((aligned(16)));
#pragma unroll
            for (int j = 0; j < 8; ++j) o[j] = sm[kc + j][cc];
            int np = 4 * (h0 + cc) + g;
            *((uint4*)(Bt + (size_t)np * KDIM + kt * 64 + kc)) = *((const uint4*)o);
        }
    }
}

// ---------------------------------------------------------------------------
// Pass 1: 256x64-tile bf16 MFMA GEMM [M=16384,K=1024] x [N'=2048,K]^T.
// 4 waves, each owning a 64x64 wave tile (acc 4x4 f32x4 = 64 regs).
// Doubles MFMA:ds_read ratio vs 128x64 (DS pipe was 56%-loaded at R3).
// XOR-swizzled LDS staging; barrier-free per-wave-scratch epilogue with
// fused LSTM-cell math. LDS 40 KB -> 4 blocks/CU.
// ---------------------------------------------------------------------------
__global__ __launch_bounds__(256, 4) void gemm_cell(const ushort_t* __restrict__ A,
                                                    const ushort_t* __restrict__ Bt,
                                                    const float* __restrict__ b,
                                                    const float* __restrict__ c_prev,
                                                    float* __restrict__ h_out,
                                                    float* __restrict__ c_out) {
    __shared__ float smem_f[10240];                // 40 KB
    ushort_t* Als = (ushort_t*)smem_f;             // 256 rows x 64 k (32 KB)
    ushort_t* Bls = Als + 256 * 64;                //  64 rows x 64 k ( 8 KB)

    const int tid  = threadIdx.x;
    const int w    = tid >> 6;
    const int lane = tid & 63;
    // XCD-aware swizzle
    int bid = blockIdx.x;                          // 2048 blocks
    int lid = (bid >> 3) + (bid & 7) * 256;
    const int m0 = (lid >> 5) * 256;               // 64 m-tiles
    const int n0 = (lid & 31) * 64;                // 32 n-tiles (permuted N)
    const int wm = w * 64;                         // wave row offset
    const int lr   = lane & 15;
    const int quad = lane >> 4;
    const int sw   = lr & 7;                       // read-side swizzle key

    f32x4 zero = {0.f, 0.f, 0.f, 0.f};
    f32x4 acc[4][4];
#pragma unroll
    for (int i = 0; i < 4; ++i)
#pragma unroll
        for (int j = 0; j < 4; ++j) acc[i][j] = zero;

    for (int kt = 0; kt < KDIM / 64; ++kt) {
        // stage tiles; LDS slot (row, ch) holds global chunk (row, ch^(row&7))
#pragma unroll
        for (int r = 0; r < 8; ++r) {              // A: slots 0..2047
            int c = r * 256 + tid;
            int trow = c >> 3;
            int chg = (c & 7) ^ (trow & 7);
            const ushort_t* ga = A + (size_t)(m0 + trow) * KDIM + kt * 64 + chg * 8;
            __builtin_amdgcn_global_load_lds(
                (const __attribute__((address_space(1))) void*)ga,
                (__attribute__((address_space(3))) void*)((char*)Als + c * 16),
                16, 0, 0);
        }
#pragma unroll
        for (int r = 0; r < 2; ++r) {              // B: slots 0..511
            int c = r * 256 + tid;
            int trow = c >> 3;
            int chg = (c & 7) ^ (trow & 7);
            const ushort_t* gb = Bt + (size_t)(n0 + trow) * KDIM + kt * 64 + chg * 8;
            __builtin_amdgcn_global_load_lds(
                (const __attribute__((address_space(1))) void*)gb,
                (__attribute__((address_space(3))) void*)((char*)Bls + c * 16),
                16, 0, 0);
        }
        __syncthreads();

#pragma unroll
        for (int kk = 0; kk < 2; ++kk) {
            bf16x8 af[4], bfr[4];
            int ch = kk * 4 + quad;
#pragma unroll
            for (int t2 = 0; t2 < 4; ++t2) {
                int ra = wm + t2 * 16 + lr;        // ra&7 == lr&7
                af[t2] = *((const bf16x8*)(Als + (ra * 8 + (ch ^ sw)) * 8));
            }
#pragma unroll
            for (int t2 = 0; t2 < 4; ++t2) {
                int rb = t2 * 16 + lr;             // rb&7 == lr&7
                bfr[t2] = *((const bf16x8*)(Bls + (rb * 8 + (ch ^ sw)) * 8));
            }
#pragma unroll
            for (int tm = 0; tm < 4; ++tm)
#pragma unroll
                for (int tn = 0; tn < 4; ++tn)
                    acc[tm][tn] = __builtin_amdgcn_mfma_f32_16x16x32_bf16(
                        af[tm], bfr[tn], acc[tm][tn], 0, 0, 0);
        }
        __syncthreads();
    }

    // ---- barrier-free epilogue: per-wave private 4 KB scratch ----
    // wave tile = 64 rows x 64 cols (16 h-indices); 4 chunks of 16 rows
    float* scr = smem_f + w * 1024;                // 16 rows x 64 cols
    const int rr = lane >> 2;                      // row within chunk
    const int hg0 = (n0 >> 2) + (lane & 3) * 4;    // 4 consecutive h per lane
    const float4 bi4 = *((const float4*)(b + hg0));
    const float4 bff = *((const float4*)(b + 512 + hg0));
    const float4 bgg = *((const float4*)(b + 1024 + hg0));
    const float4 boo = *((const float4*)(b + 1536 + hg0));
    const float bi[4] = {bi4.x, bi4.y, bi4.z, bi4.w};
    const float bfv[4] = {bff.x, bff.y, bff.z, bff.w};
    const float bg[4] = {bgg.x, bgg.y, bgg.z, bgg.w};
    const float bo[4] = {boo.x, boo.y, boo.z, boo.w};

#pragma unroll
    for (int tm = 0; tm < 4; ++tm) {
        // write 16x64 chunk, XOR-swizzled 16B col-blocks
#pragma unroll
        for (int tn = 0; tn < 4; ++tn) {
            int c = tn * 16 + lr;
#pragma unroll
            for (int rg = 0; rg < 4; ++rg) {
                int r = quad * 4 + rg;
                int blk = (c >> 2) ^ r;            // 0..15
                scr[r * 64 + blk * 4 + (c & 3)] = acc[tm][tn][rg];
            }
        }
        // same-wave in-order DS pipe: no barrier needed
        float4 gv[4];
#pragma unroll
        for (int j = 0; j < 4; ++j) {
            int cb = (lane & 3) * 4 + j;
            gv[j] = *((const float4*)(scr + rr * 64 + (cb ^ rr) * 4));
        }
        int grow = m0 + wm + tm * 16 + rr;
        float4 cp4 = *((const float4*)(c_prev + (size_t)grow * HDIM + hg0));
        const float cpv[4] = {cp4.x, cp4.y, cp4.z, cp4.w};
        float cn[4], hv[4];
#pragma unroll
        for (int j = 0; j < 4; ++j) {
            float iv = sigmoid_f(gv[j].x + bi[j]);
            float fv = sigmoid_f(gv[j].y + bfv[j]);
            float g2 = tanh_f(gv[j].z + bg[j]);
            float ov = sigmoid_f(gv[j].w + bo[j]);
            cn[j] = fv * cpv[j] + iv * g2;
            hv[j] = ov * tanh_f(cn[j]);
        }
        float4 cno = {cn[0], cn[1], cn[2], cn[3]};
        float4 hvo = {hv[0], hv[1], hv[2], hv[3]};
        *((float4*)(c_out + (size_t)grow * HDIM + hg0)) = cno;
        *((float4*)(h_out + (size_t)grow * HDIM + hg0)) = hvo;
    }
}

// ---------------------------------------------------------------------------
// Pass 2: in-place row-wise LayerNorm on h (one wave per 512-elem row)
// ---------------------------------------------------------------------------
__global__ __launch_bounds__(256) void ln_kernel(float* __restrict__ h,
                                                 const float* __restrict__ lw,
                                                 const float* __restrict__ lb) {
    int w = threadIdx.x >> 6;
    int lane = threadIdx.x & 63;
    int row = blockIdx.x * 4 + w;
    float* p = h + (size_t)row * HDIM + lane * 8;
    float4 a = ((const float4*)p)[0];
    float4 c = ((const float4*)p)[1];
    float s  = a.x + a.y + a.z + a.w + c.x + c.y + c.z + c.w;
    float ss = a.x * a.x + a.y * a.y + a.z * a.z + a.w * a.w +
               c.x * c.x + c.y * c.y + c.z * c.z + c.w * c.w;
#pragma unroll
    for (int off = 32; off > 0; off >>= 1) {
        s  += __shfl_xor(s, off);
        ss += __shfl_xor(ss, off);
    }
    float mu = s * (1.0f / 512.0f);
    float var = ss * (1.0f / 512.0f) - mu * mu;
    float rstd = rsqrtf(var + 1e-5f);
    const float* wp = lw + lane * 8;
    const float* bp = lb + lane * 8;
    float4 w0 = ((const float4*)wp)[0];
    float4 w1 = ((const float4*)wp)[1];
    float4 b0 = ((const float4*)bp)[0];
    float4 b1 = ((const float4*)bp)[1];
    a.x = (a.x - mu) * rstd * w0.x + b0.x;
    a.y = (a.y - mu) * rstd * w0.y + b0.y;
    a.z = (a.z - mu) * rstd * w0.z + b0.z;
    a.w = (a.w - mu) * rstd * w0.w + b0.w;
    c.x = (c.x - mu) * rstd * w1.x + b1.x;
    c.y = (c.y - mu) * rstd * w1.y + b1.y;
    c.z = (c.z - mu) * rstd * w1.z + b1.z;
    c.w = (c.w - mu) * rstd * w1.w + b1.w;
    ((float4*)p)[0] = a;
    ((float4*)p)[1] = c;
}

extern "C" void kernel_launch(void* const* d_in, const int* in_sizes, int n_in,
                              void* d_out, int out_size, void* d_ws, size_t ws_size,
                              hipStream_t stream) {
    const float* x      = (const float*)d_in[0];
    const float* h_prev = (const float*)d_in[1];
    const float* c_prev = (const float*)d_in[2];
    const float* W_i    = (const float*)d_in[3];
    const float* W_h    = (const float*)d_in[4];
    const float* b      = (const float*)d_in[5];
    const float* ln_w   = (const float*)d_in[6];
    const float* ln_b   = (const float*)d_in[7];

    float* h_out = (float*)d_out;                       // [16384][512]
    float* c_out = h_out + (size_t)MROWS * HDIM;        // [16384][512]

    ushort_t* A  = (ushort_t*)d_ws;                     // 32 MB
    ushort_t* Bt = A + (size_t)MROWS * KDIM;            // 4 MB

    pack_ab<<<8192 + 512, 256, 0, stream>>>(x, h_prev, W_i, W_h, A, Bt);
    gemm_cell<<<2048, 256, 0, stream>>>(A, Bt, b, c_prev, h_out, c_out);
    ln_kernel<<<MROWS / 4, 256, 0, stream>>>(h_out, ln_w, ln_b);
}